// Round 4
// baseline (12759.064 us; speedup 1.0000x reference)
//
#include <hip/hip_runtime.h>

#define N_ROWS 32768
#define DIM    512
#define NQ     4
#define NCODES 2048
#define BETA   0.25
#define EPS_RESCUE 0.01f   // score-gap (=d-gap/2) below which we np-mimic rescore ALL codes

// ---- numpy pairwise sum (blocksize 128, 8-way unrolled) of squares of 512 floats ----
// Exact replication of np.add.reduce's fp32 pairwise order for n=512:
// total = (blk0+blk1) + (blk2+blk3), blk = ((r0+r1)+(r2+r3))+((r4+r5)+(r6+r7)),
// r[j] = sequential sum of a[j], a[j+8], ..., a[j+120] (squared elementwise first).
// Lanes 0..31 are the 32 accumulator chains; every lane returns the same value.
// All ops via __f*_rn to forbid FMA contraction (must round like numpy).
__device__ __forceinline__ float np_pairwise_sq512(const float* buf, int lane) {
  const int blk = lane >> 3, j = lane & 7;
  const float* p = buf + ((lane < 32) ? (blk * 128 + j) : 0);
  float a = p[0];
  float acc = __fmul_rn(a, a);
#pragma unroll
  for (int i = 1; i < 16; ++i) {
    a = p[i * 8];
    acc = __fadd_rn(acc, __fmul_rn(a, a));
  }
  float s[4];
#pragma unroll
  for (int b = 0; b < 4; ++b) {
    const float p0 = __shfl(acc, b * 8 + 0), p1 = __shfl(acc, b * 8 + 1);
    const float p2 = __shfl(acc, b * 8 + 2), p3 = __shfl(acc, b * 8 + 3);
    const float p4 = __shfl(acc, b * 8 + 4), p5 = __shfl(acc, b * 8 + 5);
    const float p6 = __shfl(acc, b * 8 + 6), p7 = __shfl(acc, b * 8 + 7);
    s[b] = __fadd_rn(__fadd_rn(__fadd_rn(p0, p1), __fadd_rn(p2, p3)),
                     __fadd_rn(__fadd_rn(p4, p5), __fadd_rn(p6, p7)));
  }
  return __fadd_rn(__fadd_rn(s[0], s[1]), __fadd_rn(s[2], s[3]));
}

// ---------------- Cn[q][k] = np-pairwise fp32 sum(cb^2) ----------------
__global__ __launch_bounds__(64)
void cnorm_kernel(const float* __restrict__ cb, float* __restrict__ Cn) {
  const int row = blockIdx.x, lane = threadIdx.x;
  __shared__ float buf[DIM];
  const float* p = cb + (size_t)row * DIM + lane * 8;
  float4 a = *(const float4*)p, b = *(const float4*)(p + 4);
  *(float4*)&buf[lane * 8]     = a;
  *(float4*)&buf[lane * 8 + 4] = b;
  __syncthreads();
  const float v = np_pairwise_sq512(buf, lane);
  if (lane == 0) Cn[row] = v;
}

// top-2 insert with np-argmin-compatible tie-break (lower index wins on equal value)
__device__ __forceinline__ void top2_insert(float s, int c, float& v1, int& i1, float& v2, int& i2) {
  if (s > v1 || (s == v1 && c < i1)) { v2 = v1; i2 = i1; v1 = s; i1 = c; }
  else if (s > v2 || (s == v2 && c < i2)) { v2 = s; i2 = c; }
}

// ---------------- fused fp32 GEMM + top-2 argmax (main path) ----------------
__global__ __launch_bounds__(256)
void argmax_kernel(const float* __restrict__ x, const float* __restrict__ xq_acc,
                   const float* __restrict__ cb, const float* __restrict__ Cn,
                   float* __restrict__ idx_out, float* __restrict__ gap_out, int stage)
{
  __shared__ float As[64][20];   // [row][d] pad: stride 20 floats (16B-aligned, <=2-way banks)
  __shared__ float Bs[16][128];  // [d][code]

  const int t  = threadIdx.x;
  const int tx = t & 15;   // code group (8 codes each)
  const int ty = t >> 4;   // row group  (4 rows each)
  const int m0 = blockIdx.x * 64;

  const int arow = t >> 2;  // 0..63  (A staging)
  const int aseg = t & 3;   // 0..3

  float bv1[4], bv2[4];
  int   bi1[4], bi2[4];
#pragma unroll
  for (int i = 0; i < 4; ++i) {
    bv1[i] = -3.4e38f; bv2[i] = -3.4e38f;
    bi1[i] = 0x7fffffff; bi2[i] = 0x7fffffff;
  }

  for (int ct = 0; ct < NCODES / 128; ++ct) {
    float acc[4][8];
#pragma unroll
    for (int i = 0; i < 4; ++i)
#pragma unroll
      for (int j = 0; j < 8; ++j) acc[i][j] = 0.f;

    for (int dc = 0; dc < DIM / 16; ++dc) {
      const int d0 = dc * 16;
      __syncthreads();
      {
        const size_t g = (size_t)(m0 + arow) * DIM + d0 + aseg * 4;
        float4 xv = *(const float4*)(x + g);
        if (stage) {
          float4 av = *(const float4*)(xq_acc + g);
          xv.x -= av.x; xv.y -= av.y; xv.z -= av.z; xv.w -= av.w;
        }
        As[arow][aseg * 4 + 0] = xv.x;
        As[arow][aseg * 4 + 1] = xv.y;
        As[arow][aseg * 4 + 2] = xv.z;
        As[arow][aseg * 4 + 3] = xv.w;
      }
#pragma unroll
      for (int l = 0; l < 2; ++l) {
        const int lin = l * 256 + t;   // 0..511
        const int cl  = lin >> 2;      // 0..127
        const int seg = lin & 3;       // 0..3
        const size_t g = (size_t)(ct * 128 + cl) * DIM + d0 + seg * 4;
        float4 bv = *(const float4*)(cb + g);
        Bs[seg * 4 + 0][cl] = bv.x;
        Bs[seg * 4 + 1][cl] = bv.y;
        Bs[seg * 4 + 2][cl] = bv.z;
        Bs[seg * 4 + 3][cl] = bv.w;
      }
      __syncthreads();
#pragma unroll
      for (int dg = 0; dg < 4; ++dg) {
        float4 a[4];
#pragma unroll
        for (int i = 0; i < 4; ++i) a[i] = *(const float4*)&As[ty * 4 + i][dg * 4];
#pragma unroll
        for (int k = 0; k < 4; ++k) {
          float4 b0 = *(const float4*)&Bs[dg * 4 + k][tx * 8];
          float4 b1 = *(const float4*)&Bs[dg * 4 + k][tx * 8 + 4];
#pragma unroll
          for (int i = 0; i < 4; ++i) {
            const float av = (k == 0) ? a[i].x : (k == 1) ? a[i].y : (k == 2) ? a[i].z : a[i].w;
            acc[i][0] += av * b0.x; acc[i][1] += av * b0.y;
            acc[i][2] += av * b0.z; acc[i][3] += av * b0.w;
            acc[i][4] += av * b1.x; acc[i][5] += av * b1.y;
            acc[i][6] += av * b1.z; acc[i][7] += av * b1.w;
          }
        }
      }
    }
#pragma unroll
    for (int i = 0; i < 4; ++i) {
      float tv1 = -3.4e38f, tv2 = -3.4e38f;
      int   ti1 = 0x7fffffff, ti2 = 0x7fffffff;
#pragma unroll
      for (int j = 0; j < 8; ++j) {
        const int code = ct * 128 + tx * 8 + j;
        top2_insert(acc[i][j] - 0.5f * Cn[code], code, tv1, ti1, tv2, ti2);
      }
#pragma unroll
      for (int off = 1; off < 16; off <<= 1) {
        const float ov1 = __shfl_xor(tv1, off); const int oi1 = __shfl_xor(ti1, off);
        const float ov2 = __shfl_xor(tv2, off); const int oi2 = __shfl_xor(ti2, off);
        top2_insert(ov1, oi1, tv1, ti1, tv2, ti2);
        top2_insert(ov2, oi2, tv1, ti1, tv2, ti2);
      }
      top2_insert(tv1, ti1, bv1[i], bi1[i], bv2[i], bi2[i]);
      top2_insert(tv2, ti2, bv1[i], bi1[i], bv2[i], bi2[i]);
    }
  }
  if (tx == 0) {
#pragma unroll
    for (int i = 0; i < 4; ++i) {
      const int row = m0 + ty * 4 + i;
      idx_out[(size_t)row * NQ + stage] = (float)bi1[i];
      gap_out[row] = bv1[i] - bv2[i];
    }
  }
}

// ---------------- np-fp32-mimic rescue: full rescore of flagged rows ----------------
// One wave per row. Replicates the np reference pipeline:
//   r      : fp32 STE chain  r = fl32(r - fl32(r + fl32(e - r)))
//   Rn, Cn : np pairwise fp32 sums of squares
//   G      : fp64 dot rounded to fp32 (sub-ulp of the d combine grid)
//   d      : fl32( fl32(Rn + Cn) - fl32(2*G) ), argmin with first-min (lowest index) rule
__global__ __launch_bounds__(64)
void rescue_kernel(const float* __restrict__ x, const float* __restrict__ cb,
                   const float* __restrict__ Cn, float* __restrict__ idxf,
                   const float* __restrict__ gap, int stage)
{
  const int row = blockIdx.x;
  if (gap[row] >= EPS_RESCUE) return;   // block-uniform early exit (~99% of blocks)
  const int lane = threadIdx.x;
  __shared__ float rs[DIM];

  float f[8];
  {
    const float* xp = x + (size_t)row * DIM + lane * 8;
    float4 a = *(const float4*)xp, b = *(const float4*)(xp + 4);
    f[0]=a.x; f[1]=a.y; f[2]=a.z; f[3]=a.w; f[4]=b.x; f[5]=b.y; f[6]=b.z; f[7]=b.w;
  }
  for (int p = 0; p < stage; ++p) {
    const int ip = (int)idxf[(size_t)row * NQ + p];
    const float* cp = cb + ((size_t)p * NCODES + ip) * DIM + lane * 8;
    float4 a = *(const float4*)cp, b = *(const float4*)(cp + 4);
    const float q[8] = {a.x, a.y, a.z, a.w, b.x, b.y, b.z, b.w};
#pragma unroll
    for (int k = 0; k < 8; ++k) {
      const float tt = __fsub_rn(q[k], f[k]);   // sg(xq - r)
      const float xr = __fadd_rn(f[k], tt);     // x_res (STE)
      f[k] = __fsub_rn(f[k], xr);               // next residual
    }
  }
#pragma unroll
  for (int k = 0; k < 8; ++k) rs[lane * 8 + k] = f[k];
  __syncthreads();
  const float Rn = np_pairwise_sq512(rs, lane);

  const float* cbs = cb + (size_t)stage * NCODES * DIM;
  const float* Cns = Cn + stage * NCODES;
  float dbest = 3.4e38f;
  int   ibest = 0x7fffffff;
  for (int c = 0; c < NCODES; ++c) {
    const float* cp = cbs + (size_t)c * DIM + lane * 8;
    float4 a = *(const float4*)cp, b = *(const float4*)(cp + 4);
    double s = (double)f[0] * a.x + (double)f[1] * a.y + (double)f[2] * a.z + (double)f[3] * a.w
             + (double)f[4] * b.x + (double)f[5] * b.y + (double)f[6] * b.z + (double)f[7] * b.w;
#pragma unroll
    for (int off = 32; off; off >>= 1) s += __shfl_xor(s, off);
    const float G = (float)s;
    const float d = __fsub_rn(__fadd_rn(Rn, Cns[c]), __fmul_rn(2.0f, G));
    if (d < dbest || (d == dbest && c < ibest)) { dbest = d; ibest = c; }
  }
  if (lane == 0) idxf[(size_t)row * NQ + stage] = (float)ibest;
}

// ---------------- gather chosen code, accumulate x_q, accumulate loss ----------------
__global__ __launch_bounds__(128)
void update_kernel(const float* __restrict__ x, float* __restrict__ xq_acc,
                   const float* __restrict__ cb, const float* __restrict__ idxf,
                   double* __restrict__ loss_sum, int stage)
{
  const int n = blockIdx.x;
  const int t = threadIdx.x;
  const int idx = (int)idxf[(size_t)n * NQ + stage];
  const size_t g = (size_t)n * DIM + t * 4;

  float4 cv = *(const float4*)(cb + (size_t)idx * DIM + t * 4);
  float4 av;
  if (stage) av = *(const float4*)(xq_acc + g);
  else { av.x = 0.f; av.y = 0.f; av.z = 0.f; av.w = 0.f; }
  av.x += cv.x; av.y += cv.y; av.z += cv.z; av.w += cv.w;
  *(float4*)(xq_acc + g) = av;

  float4 xv = *(const float4*)(x + g);
  const float rx = xv.x - av.x, ry = xv.y - av.y, rz = xv.z - av.z, rw = xv.w - av.w;
  float s = rx * rx + ry * ry + rz * rz + rw * rw;
#pragma unroll
  for (int off = 32; off; off >>= 1) s += __shfl_down(s, off);
  __shared__ float wsum[2];
  if ((t & 63) == 0) wsum[t >> 6] = s;
  __syncthreads();
  if (t == 0) atomicAdd(loss_sum, (double)(wsum[0] + wsum[1]));
}

__global__ void finalize_kernel(const double* __restrict__ loss_sum, float* __restrict__ out_loss) {
  *out_loss = (float)(((1.0 + BETA) / ((double)NQ * (double)N_ROWS * (double)DIM)) * *loss_sum);
}

extern "C" void kernel_launch(void* const* d_in, const int* in_sizes, int n_in,
                              void* d_out, int out_size, void* d_ws, size_t ws_size,
                              hipStream_t stream) {
  const float* x  = (const float*)d_in[0];
  const float* cb = (const float*)d_in[1];

  float* out_xq   = (float*)d_out;                       // [N, D]
  float* out_loss = out_xq + (size_t)N_ROWS * DIM;       // scalar
  float* out_idx  = out_loss + 1;                        // [N, Q] as float

  double* loss_sum = (double*)d_ws;                      // [0, 8)
  float*  Cn       = (float*)((char*)d_ws + 16);         // [16, 32784): Q*K np-pairwise norms
  float*  gap      = (float*)((char*)d_ws + 32800);      // [32800, 163872): per-row top-2 gap

  hipMemsetAsync(d_ws, 0, 16, stream);                   // zero loss accumulator (ws is poisoned)
  cnorm_kernel<<<NQ * NCODES, 64, 0, stream>>>(cb, Cn);

  for (int q = 0; q < NQ; ++q) {
    const float* cbq = cb + (size_t)q * NCODES * DIM;
    argmax_kernel<<<N_ROWS / 64, 256, 0, stream>>>(x, out_xq, cbq, Cn + q * NCODES,
                                                   out_idx, gap, q);
    rescue_kernel<<<N_ROWS, 64, 0, stream>>>(x, cb, Cn, out_idx, gap, q);
    update_kernel<<<N_ROWS, 128, 0, stream>>>(x, out_xq, cbq, out_idx, loss_sum, q);
  }
  finalize_kernel<<<1, 1, 0, stream>>>(loss_sum, out_loss);
}

// Round 5
// 8668.066 us; speedup vs baseline: 1.4720x; 1.4720x over previous
//
#include <hip/hip_runtime.h>
#include <stdint.h>

#define N_ROWS 32768
#define DIM    512
#define NQ     4
#define NCODES 2048
#define BETA   0.25
#define EPS_RESCUE 0.02f   // MFMA-score gap below which we np-mimic rescore ALL codes

typedef __attribute__((ext_vector_type(8))) short bf16x8;
typedef __attribute__((ext_vector_type(4))) float f32x4;

// ---- ws layout (bytes) ----
#define WS_LOSS   0          // 512 doubles (4 KB)
#define WS_CN     4096       // Q*K floats (32 KB)
#define WS_GAP    36864      // N floats (128 KB)
#define WS_PART   167936     // 16 * N float4 (8 MB)
#define WS_CBH    8556544    // Q*K*D ushort (8 MB)
#define WS_CBL    16945152   // Q*K*D ushort (8 MB)

__device__ __forceinline__ ushort f2bf(float f) {
  union { float f; uint32_t u; } v; v.f = f;
  uint32_t r = v.u + 0x7fffu + ((v.u >> 16) & 1u);
  return (ushort)(r >> 16);
}
__device__ __forceinline__ float bf2f(ushort h) {
  union { uint32_t u; float f; } v; v.u = ((uint32_t)h) << 16; return v.f;
}

// ---- numpy pairwise sum (blocksize 128, 8-way unrolled) of squares of 512 floats ----
__device__ __forceinline__ float np_pairwise_sq512(const float* buf, int lane) {
  const int blk = lane >> 3, j = lane & 7;
  const float* p = buf + ((lane < 32) ? (blk * 128 + j) : 0);
  float a = p[0];
  float acc = __fmul_rn(a, a);
#pragma unroll
  for (int i = 1; i < 16; ++i) {
    a = p[i * 8];
    acc = __fadd_rn(acc, __fmul_rn(a, a));
  }
  float s[4];
#pragma unroll
  for (int b = 0; b < 4; ++b) {
    const float p0 = __shfl(acc, b * 8 + 0), p1 = __shfl(acc, b * 8 + 1);
    const float p2 = __shfl(acc, b * 8 + 2), p3 = __shfl(acc, b * 8 + 3);
    const float p4 = __shfl(acc, b * 8 + 4), p5 = __shfl(acc, b * 8 + 5);
    const float p6 = __shfl(acc, b * 8 + 6), p7 = __shfl(acc, b * 8 + 7);
    s[b] = __fadd_rn(__fadd_rn(__fadd_rn(p0, p1), __fadd_rn(p2, p3)),
                     __fadd_rn(__fadd_rn(p4, p5), __fadd_rn(p6, p7)));
  }
  return __fadd_rn(__fadd_rn(s[0], s[1]), __fadd_rn(s[2], s[3]));
}

__global__ __launch_bounds__(64)
void cnorm_kernel(const float* __restrict__ cb, float* __restrict__ Cn) {
  const int row = blockIdx.x, lane = threadIdx.x;
  __shared__ float buf[DIM];
  const float* p = cb + (size_t)row * DIM + lane * 8;
  float4 a = *(const float4*)p, b = *(const float4*)(p + 4);
  *(float4*)&buf[lane * 8]     = a;
  *(float4*)&buf[lane * 8 + 4] = b;
  __syncthreads();
  const float v = np_pairwise_sq512(buf, lane);
  if (lane == 0) Cn[row] = v;
}

// ---- split codebook into bf16 hi/lo ----
__global__ __launch_bounds__(256)
void cbsplit_kernel(const float* __restrict__ cb, ushort* __restrict__ hi, ushort* __restrict__ lo) {
  const size_t i = ((size_t)blockIdx.x * 256 + threadIdx.x) * 8;
  float4 a = *(const float4*)(cb + i), b = *(const float4*)(cb + i + 4);
  const float f[8] = {a.x, a.y, a.z, a.w, b.x, b.y, b.z, b.w};
  ushort h[8], l[8];
#pragma unroll
  for (int j = 0; j < 8; ++j) {
    h[j] = f2bf(f[j]);
    l[j] = f2bf(f[j] - bf2f(h[j]));
  }
  *(ushort4*)(hi + i)     = make_ushort4(h[0], h[1], h[2], h[3]);
  *(ushort4*)(hi + i + 4) = make_ushort4(h[4], h[5], h[6], h[7]);
  *(ushort4*)(lo + i)     = make_ushort4(l[0], l[1], l[2], l[3]);
  *(ushort4*)(lo + i + 4) = make_ushort4(l[4], l[5], l[6], l[7]);
}

__device__ __forceinline__ void top2_insert(float s, int c, float& v1, int& i1, float& v2, int& i2) {
  if (s > v1 || (s == v1 && c < i1)) { v2 = v1; i2 = i1; v1 = s; i1 = c; }
  else if (s > v2 || (s == v2 && c < i2)) { v2 = s; i2 = c; }
}

// ---------------- MFMA bf16x3 score + per-(rowtile,codetile) top-2 ----------------
// Block 256 (4 waves): tile 64 rows x 128 codes, K looped in chunks of 32.
// Wave w owns codes [w*32, w*32+32): n-tiles nt=0,1; m-tiles mt=0..3.
__global__ __launch_bounds__(256, 2)
void argmax_kernel(const float* __restrict__ x, const float* __restrict__ xq_acc,
                   const ushort* __restrict__ cbh, const ushort* __restrict__ cbl,
                   const float* __restrict__ Cn, float4* __restrict__ partials, int stage)
{
  __shared__ ushort Ah[64 * 32], Al[64 * 32], Bh[128 * 32], Bl[128 * 32];
  __shared__ float4 mbuf[4][64];

  const int t    = threadIdx.x;
  const int lane = t & 63, w = t >> 6;
  const int rt = blockIdx.x & 511, ct = blockIdx.x >> 9;
  const int m0 = rt * 64, c0 = ct * 128;
  const int arow = t >> 2, aseg = (t & 3) * 8;
  const int lm = lane & 15, lq = lane >> 4;

  f32x4 acc[4][2];
#pragma unroll
  for (int mt = 0; mt < 4; ++mt)
#pragma unroll
    for (int nt = 0; nt < 2; ++nt) acc[mt][nt] = (f32x4){0.f, 0.f, 0.f, 0.f};

  for (int kc = 0; kc < 16; ++kc) {
    const int k0 = kc * 32;
    __syncthreads();
    // ---- B: async global->LDS, 16B per lane (LDS addr = uniform + lane*16) ----
#pragma unroll
    for (int i = 0; i < 2; ++i) {
      const int s = i * 256 + t;                       // 0..511: code=s>>2, kseg=s&3
      const size_t g = (size_t)(c0 + (s >> 2)) * DIM + k0 + (s & 3) * 8;
      __builtin_amdgcn_global_load_lds((__attribute__((address_space(1))) void*)(cbh + g),
                                       (__attribute__((address_space(3))) void*)&Bh[s * 8], 16, 0, 0);
      __builtin_amdgcn_global_load_lds((__attribute__((address_space(1))) void*)(cbl + g),
                                       (__attribute__((address_space(3))) void*)&Bl[s * 8], 16, 0, 0);
    }
    // ---- A: load fp32 residual chunk, split hi/lo, store LDS ----
    {
      const size_t g = (size_t)(m0 + arow) * DIM + k0 + aseg;
      float4 v0 = *(const float4*)(x + g), v1 = *(const float4*)(x + g + 4);
      if (stage) {
        float4 q0 = *(const float4*)(xq_acc + g), q1 = *(const float4*)(xq_acc + g + 4);
        v0.x -= q0.x; v0.y -= q0.y; v0.z -= q0.z; v0.w -= q0.w;
        v1.x -= q1.x; v1.y -= q1.y; v1.z -= q1.z; v1.w -= q1.w;
      }
      const float f[8] = {v0.x, v0.y, v0.z, v0.w, v1.x, v1.y, v1.z, v1.w};
      ushort h[8], l[8];
#pragma unroll
      for (int j = 0; j < 8; ++j) {
        h[j] = f2bf(f[j]);
        l[j] = f2bf(f[j] - bf2f(h[j]));
      }
      const int o = arow * 32 + aseg;
      *(ushort4*)&Ah[o]     = make_ushort4(h[0], h[1], h[2], h[3]);
      *(ushort4*)&Ah[o + 4] = make_ushort4(h[4], h[5], h[6], h[7]);
      *(ushort4*)&Al[o]     = make_ushort4(l[0], l[1], l[2], l[3]);
      *(ushort4*)&Al[o + 4] = make_ushort4(l[4], l[5], l[6], l[7]);
    }
    __syncthreads();   // drains vmcnt (global_load_lds) + lgkm (ds_write)
    // ---- fragments: A[m=lm][k=lq*8+j], B[n=lm][k=lq*8+j] (B^T pattern) ----
    bf16x8 ah[4], al[4], bh[2], bl[2];
#pragma unroll
    for (int mt = 0; mt < 4; ++mt) {
      const int o = (mt * 16 + lm) * 32 + lq * 8;
      ah[mt] = *(bf16x8*)&Ah[o];
      al[mt] = *(bf16x8*)&Al[o];
    }
#pragma unroll
    for (int nt = 0; nt < 2; ++nt) {
      const int o = (w * 32 + nt * 16 + lm) * 32 + lq * 8;
      bh[nt] = *(bf16x8*)&Bh[o];
      bl[nt] = *(bf16x8*)&Bl[o];
    }
#pragma unroll
    for (int mt = 0; mt < 4; ++mt)
#pragma unroll
      for (int nt = 0; nt < 2; ++nt) {
        acc[mt][nt] = __builtin_amdgcn_mfma_f32_16x16x32_bf16(ah[mt], bh[nt], acc[mt][nt], 0, 0, 0);
        acc[mt][nt] = __builtin_amdgcn_mfma_f32_16x16x32_bf16(ah[mt], bl[nt], acc[mt][nt], 0, 0, 0);
        acc[mt][nt] = __builtin_amdgcn_mfma_f32_16x16x32_bf16(al[mt], bh[nt], acc[mt][nt], 0, 0, 0);
      }
  }
  // ---- epilogue: score = G - 0.5*||c||^2; top-2 per row across wave's 32 codes ----
  float hc[2]; int cidx[2];
#pragma unroll
  for (int nt = 0; nt < 2; ++nt) {
    cidx[nt] = c0 + w * 32 + nt * 16 + lm;
    hc[nt] = 0.5f * Cn[cidx[nt]];
  }
#pragma unroll
  for (int mt = 0; mt < 4; ++mt)
#pragma unroll
    for (int r = 0; r < 4; ++r) {
      float v1 = -3.4e38f, v2 = -3.4e38f;
      int   i1 = 0x7fffffff, i2 = 0x7fffffff;
#pragma unroll
      for (int nt = 0; nt < 2; ++nt)
        top2_insert(acc[mt][nt][r] - hc[nt], cidx[nt], v1, i1, v2, i2);
#pragma unroll
      for (int off = 1; off < 16; off <<= 1) {   // stays within the 16-lane quad group
        const float ov1 = __shfl_xor(v1, off); const int oi1 = __shfl_xor(i1, off);
        const float ov2 = __shfl_xor(v2, off); const int oi2 = __shfl_xor(i2, off);
        top2_insert(ov1, oi1, v1, i1, v2, i2);
        top2_insert(ov2, oi2, v1, i1, v2, i2);
      }
      if (lm == 0) mbuf[w][mt * 16 + lq * 4 + r] = make_float4(v1, (float)i1, v2, (float)i2);
    }
  __syncthreads();
  if (t < 64) {   // merge the 4 waves' top-2 for row t
    float v1 = -3.4e38f, v2 = -3.4e38f;
    int   i1 = 0x7fffffff, i2 = 0x7fffffff;
#pragma unroll
    for (int ww = 0; ww < 4; ++ww) {
      float4 p = mbuf[ww][t];
      top2_insert(p.x, (int)p.y, v1, i1, v2, i2);
      top2_insert(p.z, (int)p.w, v1, i1, v2, i2);
    }
    partials[(size_t)ct * N_ROWS + m0 + t] = make_float4(v1, (float)i1, v2, (float)i2);
  }
}

// ---- merge 16 code-tile partials per row -> idx + gap ----
__global__ __launch_bounds__(256)
void mergetop_kernel(const float4* __restrict__ partials, float* __restrict__ idx_out,
                     float* __restrict__ gap, int stage)
{
  const int row = blockIdx.x * 256 + threadIdx.x;
  float v1 = -3.4e38f, v2 = -3.4e38f;
  int   i1 = 0x7fffffff, i2 = 0x7fffffff;
#pragma unroll
  for (int ctt = 0; ctt < 16; ++ctt) {
    float4 p = partials[(size_t)ctt * N_ROWS + row];
    top2_insert(p.x, (int)p.y, v1, i1, v2, i2);
    top2_insert(p.z, (int)p.w, v1, i1, v2, i2);
  }
  idx_out[(size_t)row * NQ + stage] = (float)i1;
  gap[row] = v1 - v2;
}

// ---------------- np-fp32-mimic rescue (validated in R4) ----------------
__global__ __launch_bounds__(64)
void rescue_kernel(const float* __restrict__ x, const float* __restrict__ cb,
                   const float* __restrict__ Cn, float* __restrict__ idxf,
                   const float* __restrict__ gap, int stage)
{
  const int row = blockIdx.x;
  if (gap[row] >= EPS_RESCUE) return;
  const int lane = threadIdx.x;
  __shared__ float rs[DIM];

  float f[8];
  {
    const float* xp = x + (size_t)row * DIM + lane * 8;
    float4 a = *(const float4*)xp, b = *(const float4*)(xp + 4);
    f[0]=a.x; f[1]=a.y; f[2]=a.z; f[3]=a.w; f[4]=b.x; f[5]=b.y; f[6]=b.z; f[7]=b.w;
  }
  for (int p = 0; p < stage; ++p) {
    const int ip = (int)idxf[(size_t)row * NQ + p];
    const float* cp = cb + ((size_t)p * NCODES + ip) * DIM + lane * 8;
    float4 a = *(const float4*)cp, b = *(const float4*)(cp + 4);
    const float q[8] = {a.x, a.y, a.z, a.w, b.x, b.y, b.z, b.w};
#pragma unroll
    for (int k = 0; k < 8; ++k) {
      const float tt = __fsub_rn(q[k], f[k]);   // sg(xq - r)
      const float xr = __fadd_rn(f[k], tt);     // x_res (STE)
      f[k] = __fsub_rn(f[k], xr);               // next residual
    }
  }
#pragma unroll
  for (int k = 0; k < 8; ++k) rs[lane * 8 + k] = f[k];
  __syncthreads();
  const float Rn = np_pairwise_sq512(rs, lane);

  const float* cbs = cb + (size_t)stage * NCODES * DIM;
  const float* Cns = Cn + stage * NCODES;
  float dbest = 3.4e38f;
  int   ibest = 0x7fffffff;
  for (int c = 0; c < NCODES; ++c) {
    const float* cp = cbs + (size_t)c * DIM + lane * 8;
    float4 a = *(const float4*)cp, b = *(const float4*)(cp + 4);
    double s = (double)f[0] * a.x + (double)f[1] * a.y + (double)f[2] * a.z + (double)f[3] * a.w
             + (double)f[4] * b.x + (double)f[5] * b.y + (double)f[6] * b.z + (double)f[7] * b.w;
#pragma unroll
    for (int off = 32; off; off >>= 1) s += __shfl_xor(s, off);
    const float G = (float)s;
    const float d = __fsub_rn(__fadd_rn(Rn, Cns[c]), __fmul_rn(2.0f, G));
    if (d < dbest || (d == dbest && c < ibest)) { dbest = d; ibest = c; }
  }
  if (lane == 0) idxf[(size_t)row * NQ + stage] = (float)ibest;
}

// ---------------- gather chosen code, accumulate x_q, accumulate loss ----------------
__global__ __launch_bounds__(128)
void update_kernel(const float* __restrict__ x, float* __restrict__ xq_acc,
                   const float* __restrict__ cb, const float* __restrict__ idxf,
                   double* __restrict__ loss_arr, int stage)
{
  const int n = blockIdx.x;
  const int t = threadIdx.x;
  const int idx = (int)idxf[(size_t)n * NQ + stage];
  const size_t g = (size_t)n * DIM + t * 4;

  float4 cv = *(const float4*)(cb + (size_t)idx * DIM + t * 4);
  float4 av;
  if (stage) av = *(const float4*)(xq_acc + g);
  else { av.x = 0.f; av.y = 0.f; av.z = 0.f; av.w = 0.f; }
  av.x += cv.x; av.y += cv.y; av.z += cv.z; av.w += cv.w;
  *(float4*)(xq_acc + g) = av;

  float4 xv = *(const float4*)(x + g);
  const float rx = xv.x - av.x, ry = xv.y - av.y, rz = xv.z - av.z, rw = xv.w - av.w;
  float s = rx * rx + ry * ry + rz * rz + rw * rw;
#pragma unroll
  for (int off = 32; off; off >>= 1) s += __shfl_down(s, off);
  __shared__ float wsum[2];
  if ((t & 63) == 0) wsum[t >> 6] = s;
  __syncthreads();
  if (t == 0) atomicAdd(&loss_arr[n & 511], (double)(wsum[0] + wsum[1]));  // 512-way fan-out
}

__global__ __launch_bounds__(64)
void finalize_kernel(const double* __restrict__ loss_arr, float* __restrict__ out_loss) {
  double s = 0.0;
  for (int i = threadIdx.x; i < 512; i += 64) s += loss_arr[i];
#pragma unroll
  for (int off = 32; off; off >>= 1) s += __shfl_down(s, off);
  if (threadIdx.x == 0)
    *out_loss = (float)(((1.0 + BETA) / ((double)NQ * (double)N_ROWS * (double)DIM)) * s);
}

extern "C" void kernel_launch(void* const* d_in, const int* in_sizes, int n_in,
                              void* d_out, int out_size, void* d_ws, size_t ws_size,
                              hipStream_t stream) {
  const float* x  = (const float*)d_in[0];
  const float* cb = (const float*)d_in[1];

  float* out_xq   = (float*)d_out;                       // [N, D]
  float* out_loss = out_xq + (size_t)N_ROWS * DIM;       // scalar
  float* out_idx  = out_loss + 1;                        // [N, Q] as float

  char* ws = (char*)d_ws;
  double* loss_arr = (double*)(ws + WS_LOSS);
  float*  Cn       = (float*) (ws + WS_CN);
  float*  gap      = (float*) (ws + WS_GAP);
  float4* partials = (float4*)(ws + WS_PART);
  ushort* cb_hi    = (ushort*)(ws + WS_CBH);
  ushort* cb_lo    = (ushort*)(ws + WS_CBL);

  hipMemsetAsync(ws + WS_LOSS, 0, 4096, stream);
  cbsplit_kernel<<<(NQ * NCODES * DIM) / 2048, 256, 0, stream>>>(cb, cb_hi, cb_lo);
  cnorm_kernel<<<NQ * NCODES, 64, 0, stream>>>(cb, Cn);

  for (int q = 0; q < NQ; ++q) {
    const float* cbq = cb + (size_t)q * NCODES * DIM;
    argmax_kernel<<<512 * 16, 256, 0, stream>>>(x, out_xq,
                                                cb_hi + (size_t)q * NCODES * DIM,
                                                cb_lo + (size_t)q * NCODES * DIM,
                                                Cn + q * NCODES, partials, q);
    mergetop_kernel<<<N_ROWS / 256, 256, 0, stream>>>(partials, out_idx, gap, q);
    rescue_kernel<<<N_ROWS, 64, 0, stream>>>(x, cb, Cn, out_idx, gap, q);
    update_kernel<<<N_ROWS, 128, 0, stream>>>(x, out_xq, cbq, out_idx, loss_arr, q);
  }
  finalize_kernel<<<1, 64, 0, stream>>>(loss_arr, out_loss);
}